// Round 2
// baseline (435.367 us; speedup 1.0000x reference)
//
#include <hip/hip_runtime.h>
#include <math.h>

#define NEG_INF (-INFINITY)
#define BX 64   // lanes per row-segment: 64 * float4 = 256 columns
#define BY 4    // row-strips per block
#define RPT 8   // output rows per thread

// out0[i][j] = max(c0[i][j], c1[i][j], c0[i+1][j], c0[i][j+1], c0[i+1][j+1])
// out1[i][j] = max(c1[i][j], c1[i+1][j], c1[i][j+1], c1[i+1][j+1], c0[i+1][j+1])
// Thread strip-mines RPT rows: row i+1 is loaded once, used as "bottom" for
// row i and carried in registers as "top" for row i+1  -> (R+1)/R fetch/row.
__global__ __launch_bounds__(BX * BY) void quincunx_pool_kernel(
    const float* __restrict__ c0, const float* __restrict__ c1,
    float* __restrict__ out, long N /* elems per coset */)
{
    const int H = 512, W = 512;
    const int tx = threadIdx.x;
    const int j4 = (blockIdx.x * BX + tx) * 4;
    const int strip = blockIdx.y * BY + threadIdx.y;
    const int i0 = strip * RPT;
    const long plane_base = (long)blockIdx.z * (long)(H * W);

    long off = plane_base + (long)i0 * W + j4;

    const bool edge = (tx == BX - 1);        // last lane of the wave segment
    const bool hasJ = (j4 + 4) < W;          // j+1 spill column exists

    // Top row of the strip (always in range: i0 <= H - RPT).
    float4 a0 = *(const float4*)(c0 + off);
    float4 b0 = *(const float4*)(c1 + off);
    // j+1 spill element = next lane's .x (wave-wide shuffle), global load for lane 63.
    float a0e = __shfl_down(a0.x, 1, 64);
    float b0e = __shfl_down(b0.x, 1, 64);
    if (edge) {
        a0e = hasJ ? c0[off + 4] : NEG_INF;
        b0e = hasJ ? c1[off + 4] : NEG_INF;
    }

    #pragma unroll
    for (int r = 0; r < RPT; ++r) {
        const int i1 = i0 + r + 1;
        float4 a1, b1;
        float a1e, b1e;
        if (i1 < H) {   // wave-uniform branch (false only for last strip, last r)
            a1 = *(const float4*)(c0 + off + W);
            b1 = *(const float4*)(c1 + off + W);
            a1e = __shfl_down(a1.x, 1, 64);
            b1e = __shfl_down(b1.x, 1, 64);
            if (edge) {
                a1e = hasJ ? c0[off + W + 4] : NEG_INF;
                b1e = hasJ ? c1[off + W + 4] : NEG_INF;
            }
        } else {
            a1 = make_float4(NEG_INF, NEG_INF, NEG_INF, NEG_INF);
            b1 = a1;
            a1e = NEG_INF;
            b1e = NEG_INF;
        }

        float4 o0, o1;
        o0.x = fmaxf(fmaxf(fmaxf(a0.x, b0.x), fmaxf(a1.x, a0.y)), a1.y);
        o1.x = fmaxf(fmaxf(fmaxf(b0.x, b1.x), fmaxf(b0.y, b1.y)), a1.y);
        o0.y = fmaxf(fmaxf(fmaxf(a0.y, b0.y), fmaxf(a1.y, a0.z)), a1.z);
        o1.y = fmaxf(fmaxf(fmaxf(b0.y, b1.y), fmaxf(b0.z, b1.z)), a1.z);
        o0.z = fmaxf(fmaxf(fmaxf(a0.z, b0.z), fmaxf(a1.z, a0.w)), a1.w);
        o1.z = fmaxf(fmaxf(fmaxf(b0.z, b1.z), fmaxf(b0.w, b1.w)), a1.w);
        o0.w = fmaxf(fmaxf(fmaxf(a0.w, b0.w), fmaxf(a1.w, a0e)), a1e);
        o1.w = fmaxf(fmaxf(fmaxf(b0.w, b1.w), fmaxf(b0e, b1e)), a1e);

        *(float4*)(out + off)     = o0;
        *(float4*)(out + N + off) = o1;

        // carry bottom row -> next iteration's top row
        a0 = a1; b0 = b1; a0e = a1e; b0e = b1e;
        off += W;
    }
}

extern "C" void kernel_launch(void* const* d_in, const int* in_sizes, int n_in,
                              void* d_out, int out_size, void* d_ws, size_t ws_size,
                              hipStream_t stream) {
    const float* c0 = (const float*)d_in[0];
    const float* c1 = (const float*)d_in[1];
    float* out = (float*)d_out;

    const int H = 512, W = 512;
    long N = (long)in_sizes[0];                 // 4*32*512*512 per coset
    int planes = (int)(N / (long)(H * W));      // B*C = 128

    dim3 block(BX, BY);
    dim3 grid(W / (4 * BX),                     // 2 column segments
              H / (RPT * BY),                   // 16 strip groups
              planes);                          // 128 planes

    quincunx_pool_kernel<<<grid, block, 0, stream>>>(c0, c1, out, N);
}